// Round 1
// baseline (843.430 us; speedup 1.0000x reference)
//
#include <hip/hip_runtime.h>

#define P 32
#define CIN 10
#define COUT 64
#define NG 5
#define EPSV 1e-3f

__device__ __forceinline__ float4 f4zero() { return make_float4(0.f, 0.f, 0.f, 0.f); }
__device__ __forceinline__ void f4add(float4& a, const float4& b) {
    a.x += b.x; a.y += b.y; a.z += b.z; a.w += b.w;
}
__device__ __forceinline__ void f4maxi(float4& a, const float4& b) {
    a.x = fmaxf(a.x, b.x); a.y = fmaxf(a.y, b.y); a.z = fmaxf(a.z, b.z); a.w = fmaxf(a.w, b.w);
}
__device__ __forceinline__ int group_of(int nv) {
    return nv < 2 ? 0 : nv < 3 ? 1 : nv < 4 ? 2 : nv < 16 ? 3 : 4;
}

// ---------------- Kernel A: per-group sum / sumsq / voxel count ----------------
__global__ __launch_bounds__(256) void stats_kernel(
    const float* __restrict__ inputs, const int* __restrict__ num,
    const float* __restrict__ W, float* __restrict__ gsum,
    float* __restrict__ gsq, float* __restrict__ gcnt, int N)
{
    __shared__ float Ws[NG * CIN * COUT];   // 3200 floats
    __shared__ float ins[P * CIN];          // 320 floats
    __shared__ float4 reds[64];
    __shared__ float4 redq[64];

    const int tid = threadIdx.x;
    for (int i = tid; i < NG * CIN * COUT / 4; i += 256)
        ((float4*)Ws)[i] = ((const float4*)W)[i];

    float4 as0 = f4zero(), as1 = f4zero(), as2 = f4zero(), as3 = f4zero(), as4 = f4zero();
    float4 aq0 = f4zero(), aq1 = f4zero(), aq2 = f4zero(), aq3 = f4zero(), aq4 = f4zero();
    int c0 = 0, c1 = 0, c2 = 0, c3 = 0, c4n = 0;

    const int c4 = tid & 15;   // channel group: channels 4*c4 .. 4*c4+3
    const int pb = tid >> 4;   // point base: points pb and pb+16

    __syncthreads();
    for (int v = blockIdx.x; v < N; v += gridDim.x) {
        const int g = group_of(num[v]);
        if (tid < P * CIN / 4)
            ((float4*)ins)[tid] = ((const float4*)inputs)[(size_t)v * (P * CIN / 4) + tid];
        __syncthreads();
        const float4* Wg = (const float4*)(Ws + g * CIN * COUT);
        float4 s = f4zero(), q = f4zero();
        #pragma unroll
        for (int pp = 0; pp < 2; ++pp) {
            const int p = pb + pp * 16;
            float4 acc = f4zero();
            #pragma unroll
            for (int i = 0; i < CIN; ++i) {
                const float a = ins[p * CIN + i];
                const float4 w = Wg[i * 16 + c4];
                acc.x = fmaf(a, w.x, acc.x);
                acc.y = fmaf(a, w.y, acc.y);
                acc.z = fmaf(a, w.z, acc.z);
                acc.w = fmaf(a, w.w, acc.w);
            }
            f4add(s, acc);
            q.x = fmaf(acc.x, acc.x, q.x);
            q.y = fmaf(acc.y, acc.y, q.y);
            q.z = fmaf(acc.z, acc.z, q.z);
            q.w = fmaf(acc.w, acc.w, q.w);
        }
        // g is block-uniform for this voxel -> no divergence
        switch (g) {
            case 0: f4add(as0, s); f4add(aq0, q); if (!tid) c0++;  break;
            case 1: f4add(as1, s); f4add(aq1, q); if (!tid) c1++;  break;
            case 2: f4add(as2, s); f4add(aq2, q); if (!tid) c2++;  break;
            case 3: f4add(as3, s); f4add(aq3, q); if (!tid) c3++;  break;
            default: f4add(as4, s); f4add(aq4, q); if (!tid) c4n++; break;
        }
        __syncthreads();
    }

    // Block-level reduction over the 16 point-base slots, then one atomic set per block
    float4 AS[NG] = {as0, as1, as2, as3, as4};
    float4 AQ[NG] = {aq0, aq1, aq2, aq3, aq4};
    const int lane = tid & 63;
    const int wv = tid >> 6;
    #pragma unroll
    for (int gi = 0; gi < NG; ++gi) {
        float4 s = AS[gi], q = AQ[gi];
        #pragma unroll
        for (int m = 16; m <= 32; m <<= 1) {
            s.x += __shfl_xor(s.x, m); s.y += __shfl_xor(s.y, m);
            s.z += __shfl_xor(s.z, m); s.w += __shfl_xor(s.w, m);
            q.x += __shfl_xor(q.x, m); q.y += __shfl_xor(q.y, m);
            q.z += __shfl_xor(q.z, m); q.w += __shfl_xor(q.w, m);
        }
        if (lane < 16) { reds[wv * 16 + lane] = s; redq[wv * 16 + lane] = q; }
        __syncthreads();
        if (tid < 16) {
            float4 S = reds[tid], Q = redq[tid];
            f4add(S, reds[16 + tid]); f4add(S, reds[32 + tid]); f4add(S, reds[48 + tid]);
            f4add(Q, redq[16 + tid]); f4add(Q, redq[32 + tid]); f4add(Q, redq[48 + tid]);
            atomicAdd(&gsum[gi * COUT + tid * 4 + 0], S.x);
            atomicAdd(&gsum[gi * COUT + tid * 4 + 1], S.y);
            atomicAdd(&gsum[gi * COUT + tid * 4 + 2], S.z);
            atomicAdd(&gsum[gi * COUT + tid * 4 + 3], S.w);
            atomicAdd(&gsq[gi * COUT + tid * 4 + 0], Q.x);
            atomicAdd(&gsq[gi * COUT + tid * 4 + 1], Q.y);
            atomicAdd(&gsq[gi * COUT + tid * 4 + 2], Q.z);
            atomicAdd(&gsq[gi * COUT + tid * 4 + 3], Q.w);
        }
        __syncthreads();
    }
    if (tid == 0) {
        const int CN[NG] = {c0, c1, c2, c3, c4n};
        #pragma unroll
        for (int gi = 0; gi < NG; ++gi)
            if (CN[gi]) atomicAdd(&gcnt[gi], (float)CN[gi]);
    }
}

// ---------------- Kernel B: fold BN stats into scale/shift ----------------
__global__ __launch_bounds__(NG * COUT) void norm_kernel(
    const float* __restrict__ gsum, const float* __restrict__ gsq,
    const float* __restrict__ gcnt, const float* __restrict__ gamma,
    const float* __restrict__ beta, float* __restrict__ scale,
    float* __restrict__ shift)
{
    const int t = threadIdx.x;          // 320 threads; t = g*64 + c
    const int g = t >> 6;
    const float cnt = gcnt[g] * (float)P;
    const float denom = fmaxf(cnt, 1.f);
    const float mean = gsum[t] / denom;
    const float var = gsq[t] / denom - mean * mean;
    const float sc = gamma[t] * rsqrtf(var + EPSV);
    scale[t] = sc;
    shift[t] = fmaf(-mean, sc, beta[t]);
}

// ---------------- Kernel C: recompute x, normalize, relu, max-over-P, write ----------------
__global__ __launch_bounds__(256) void out_kernel(
    const float* __restrict__ inputs, const int* __restrict__ num,
    const float* __restrict__ W, const float* __restrict__ scale,
    const float* __restrict__ shift, float* __restrict__ out, int N)
{
    __shared__ float Ws[NG * CIN * COUT];
    __shared__ float4 scs[NG * 16];
    __shared__ float4 shs[NG * 16];
    __shared__ float ins[P * CIN];
    __shared__ float4 redm[64];

    const int tid = threadIdx.x;
    for (int i = tid; i < NG * CIN * COUT / 4; i += 256)
        ((float4*)Ws)[i] = ((const float4*)W)[i];
    if (tid < NG * 16) {
        scs[tid] = ((const float4*)scale)[tid];
        shs[tid] = ((const float4*)shift)[tid];
    }

    const int c4 = tid & 15;
    const int pb = tid >> 4;
    const int lane = tid & 63;
    const int wv = tid >> 6;

    __syncthreads();
    for (int v = blockIdx.x; v < N; v += gridDim.x) {
        const int g = group_of(num[v]);
        if (tid < P * CIN / 4)
            ((float4*)ins)[tid] = ((const float4*)inputs)[(size_t)v * (P * CIN / 4) + tid];
        __syncthreads();
        const float4* Wg = (const float4*)(Ws + g * CIN * COUT);
        const float4 sc = scs[g * 16 + c4];
        const float4 sh = shs[g * 16 + c4];
        float4 m = f4zero();  // relu output >= 0, so 0 is a safe identity
        #pragma unroll
        for (int pp = 0; pp < 2; ++pp) {
            const int p = pb + pp * 16;
            float4 acc = f4zero();
            #pragma unroll
            for (int i = 0; i < CIN; ++i) {
                const float a = ins[p * CIN + i];
                const float4 w = Wg[i * 16 + c4];
                acc.x = fmaf(a, w.x, acc.x);
                acc.y = fmaf(a, w.y, acc.y);
                acc.z = fmaf(a, w.z, acc.z);
                acc.w = fmaf(a, w.w, acc.w);
            }
            float4 y;
            y.x = fmaxf(fmaf(acc.x, sc.x, sh.x), 0.f);
            y.y = fmaxf(fmaf(acc.y, sc.y, sh.y), 0.f);
            y.z = fmaxf(fmaf(acc.z, sc.z, sh.z), 0.f);
            y.w = fmaxf(fmaf(acc.w, sc.w, sh.w), 0.f);
            ((float4*)out)[((size_t)v * P + p) * 32 + c4] = y;
            f4maxi(m, y);
        }
        // max over the 16 point-base slots: shfl within wave (4), LDS across waves (4)
        #pragma unroll
        for (int msk = 16; msk <= 32; msk <<= 1) {
            m.x = fmaxf(m.x, __shfl_xor(m.x, msk));
            m.y = fmaxf(m.y, __shfl_xor(m.y, msk));
            m.z = fmaxf(m.z, __shfl_xor(m.z, msk));
            m.w = fmaxf(m.w, __shfl_xor(m.w, msk));
        }
        if (lane < 16) redm[wv * 16 + lane] = m;
        __syncthreads();
        float4 M = redm[c4];
        f4maxi(M, redm[16 + c4]);
        f4maxi(M, redm[32 + c4]);
        f4maxi(M, redm[48 + c4]);
        #pragma unroll
        for (int pp = 0; pp < 2; ++pp) {
            const int p = pb + pp * 16;
            ((float4*)out)[((size_t)v * P + p) * 32 + 16 + c4] = M;
        }
        __syncthreads();
    }
}

extern "C" void kernel_launch(void* const* d_in, const int* in_sizes, int n_in,
                              void* d_out, int out_size, void* d_ws, size_t ws_size,
                              hipStream_t stream)
{
    (void)n_in; (void)out_size; (void)ws_size;
    const float* inputs = (const float*)d_in[0];
    const int*   num    = (const int*)d_in[1];
    const float* W      = (const float*)d_in[2];
    const float* gamma  = (const float*)d_in[3];
    const float* beta   = (const float*)d_in[4];
    float* out = (float*)d_out;
    const int N = in_sizes[1];

    float* ws    = (float*)d_ws;
    float* gsum  = ws;          // 320
    float* gsq   = ws + 320;    // 320
    float* gcnt  = ws + 640;    // 5 (pad to 656 for 16B alignment of scale)
    float* scale = ws + 656;    // 320
    float* shift = ws + 976;    // 320

    hipMemsetAsync(d_ws, 0, 648 * sizeof(float), stream);

    int gridA = N < 512 ? N : 512;
    stats_kernel<<<gridA, 256, 0, stream>>>(inputs, num, W, gsum, gsq, gcnt, N);
    norm_kernel<<<1, NG * COUT, 0, stream>>>(gsum, gsq, gcnt, gamma, beta, scale, shift);
    int gridC = (N + 7) / 8;
    if (gridC > 5000) gridC = 5000;
    if (gridC < 1) gridC = 1;
    out_kernel<<<gridC, 256, 0, stream>>>(inputs, num, W, scale, shift, out, N);
}

// Round 2
// 837.816 us; speedup vs baseline: 1.0067x; 1.0067x over previous
//
#include <hip/hip_runtime.h>

#define P 32
#define CIN 10
#define COUT 64
#define NG 5
#define EPSV 1e-3f

__device__ __forceinline__ int group_of(int nv) {
    return nv < 2 ? 0 : nv < 3 ? 1 : nv < 4 ? 2 : nv < 16 ? 3 : 4;
}

__device__ __forceinline__ float4 f4zero() { return make_float4(0.f, 0.f, 0.f, 0.f); }

// acc(4ch) = row[0..9] . w[0..9]   (row is 8B-aligned: p*10 floats)
__device__ __forceinline__ float4 dot_row(const float* __restrict__ row,
                                          const float4* __restrict__ w) {
    const float2* r = (const float2*)row;
    const float2 a0 = r[0], a1 = r[1], a2 = r[2], a3 = r[3], a4 = r[4];
    float4 acc;
    acc.x = a0.x * w[0].x; acc.y = a0.x * w[0].y; acc.z = a0.x * w[0].z; acc.w = a0.x * w[0].w;
    acc.x = fmaf(a0.y, w[1].x, acc.x); acc.y = fmaf(a0.y, w[1].y, acc.y);
    acc.z = fmaf(a0.y, w[1].z, acc.z); acc.w = fmaf(a0.y, w[1].w, acc.w);
    acc.x = fmaf(a1.x, w[2].x, acc.x); acc.y = fmaf(a1.x, w[2].y, acc.y);
    acc.z = fmaf(a1.x, w[2].z, acc.z); acc.w = fmaf(a1.x, w[2].w, acc.w);
    acc.x = fmaf(a1.y, w[3].x, acc.x); acc.y = fmaf(a1.y, w[3].y, acc.y);
    acc.z = fmaf(a1.y, w[3].z, acc.z); acc.w = fmaf(a1.y, w[3].w, acc.w);
    acc.x = fmaf(a2.x, w[4].x, acc.x); acc.y = fmaf(a2.x, w[4].y, acc.y);
    acc.z = fmaf(a2.x, w[4].z, acc.z); acc.w = fmaf(a2.x, w[4].w, acc.w);
    acc.x = fmaf(a2.y, w[5].x, acc.x); acc.y = fmaf(a2.y, w[5].y, acc.y);
    acc.z = fmaf(a2.y, w[5].z, acc.z); acc.w = fmaf(a2.y, w[5].w, acc.w);
    acc.x = fmaf(a3.x, w[6].x, acc.x); acc.y = fmaf(a3.x, w[6].y, acc.y);
    acc.z = fmaf(a3.x, w[6].z, acc.z); acc.w = fmaf(a3.x, w[6].w, acc.w);
    acc.x = fmaf(a3.y, w[7].x, acc.x); acc.y = fmaf(a3.y, w[7].y, acc.y);
    acc.z = fmaf(a3.y, w[7].z, acc.z); acc.w = fmaf(a3.y, w[7].w, acc.w);
    acc.x = fmaf(a4.x, w[8].x, acc.x); acc.y = fmaf(a4.x, w[8].y, acc.y);
    acc.z = fmaf(a4.x, w[8].z, acc.z); acc.w = fmaf(a4.x, w[8].w, acc.w);
    acc.x = fmaf(a4.y, w[9].x, acc.x); acc.y = fmaf(a4.y, w[9].y, acc.y);
    acc.z = fmaf(a4.y, w[9].z, acc.z); acc.w = fmaf(a4.y, w[9].w, acc.w);
    return acc;
}

// ---------------- Kernel A: per-group sum / sumsq / voxel count ----------------
// One wave per voxel iteration; NO __syncthreads in the main loop.
__global__ __launch_bounds__(256) void stats_kernel(
    const float* __restrict__ inputs, const int* __restrict__ num,
    const float* __restrict__ W, float* __restrict__ gsum,
    float* __restrict__ gsq, float* __restrict__ gcnt, int N)
{
    __shared__ float Ws[NG * CIN * COUT];        // 12.8 KB
    __shared__ float4 redS[4][NG][16];           // 5 KB, wave-private slots
    __shared__ float4 redQ[4][NG][16];           // 5 KB
    __shared__ int   redC[4][NG];

    const int tid = threadIdx.x;
    for (int i = tid; i < NG * CIN * COUT / 4; i += 256)
        ((float4*)Ws)[i] = ((const float4*)W)[i];
    for (int i = tid; i < 4 * NG * 16; i += 256) {
        ((float4*)redS)[i] = f4zero();
        ((float4*)redQ)[i] = f4zero();
    }
    if (tid < 4 * NG) ((int*)redC)[tid] = 0;
    __syncthreads();

    const int lane = tid & 63, wv = tid >> 6;
    const int c4 = lane & 15, pb = lane >> 4;
    const int gw = blockIdx.x * 4 + wv;
    const int stride = gridDim.x * 4;
    int cnt0 = 0, cnt1 = 0, cnt2 = 0, cnt3 = 0, cnt4 = 0;

    for (int v = gw; v < N; v += stride) {
        const int g = group_of(num[v]);
        const float* inrow = inputs + (size_t)v * (P * CIN);
        float4 w[CIN];
        const float4* Wg = (const float4*)(Ws + g * CIN * COUT);
        #pragma unroll
        for (int i = 0; i < CIN; ++i) w[i] = Wg[i * 16 + c4];

        float4 s = f4zero(), q = f4zero();
        #pragma unroll
        for (int k = 0; k < 8; ++k) {
            const int p = pb + k * 4;
            const float4 acc = dot_row(inrow + p * CIN, w);
            s.x += acc.x; s.y += acc.y; s.z += acc.z; s.w += acc.w;
            q.x = fmaf(acc.x, acc.x, q.x); q.y = fmaf(acc.y, acc.y, q.y);
            q.z = fmaf(acc.z, acc.z, q.z); q.w = fmaf(acc.w, acc.w, q.w);
        }
        #pragma unroll
        for (int msk = 16; msk <= 32; msk <<= 1) {
            s.x += __shfl_xor(s.x, msk); s.y += __shfl_xor(s.y, msk);
            s.z += __shfl_xor(s.z, msk); s.w += __shfl_xor(s.w, msk);
            q.x += __shfl_xor(q.x, msk); q.y += __shfl_xor(q.y, msk);
            q.z += __shfl_xor(q.z, msk); q.w += __shfl_xor(q.w, msk);
        }
        if (lane < 16) {  // wave-private slot: no cross-wave race, same-lane dep handled by lgkmcnt
            float4 S = redS[wv][g][c4];
            S.x += s.x; S.y += s.y; S.z += s.z; S.w += s.w;
            redS[wv][g][c4] = S;
            float4 Q = redQ[wv][g][c4];
            Q.x += q.x; Q.y += q.y; Q.z += q.z; Q.w += q.w;
            redQ[wv][g][c4] = Q;
        }
        switch (g) {
            case 0: cnt0++; break; case 1: cnt1++; break; case 2: cnt2++; break;
            case 3: cnt3++; break; default: cnt4++; break;
        }
    }
    if (lane == 0) {
        redC[wv][0] = cnt0; redC[wv][1] = cnt1; redC[wv][2] = cnt2;
        redC[wv][3] = cnt3; redC[wv][4] = cnt4;
    }
    __syncthreads();

    if (tid < NG * 16) {
        const int g = tid >> 4, c = tid & 15;
        float4 S = redS[0][g][c], Q = redQ[0][g][c];
        #pragma unroll
        for (int wvi = 1; wvi < 4; ++wvi) {
            const float4 s2 = redS[wvi][g][c], q2 = redQ[wvi][g][c];
            S.x += s2.x; S.y += s2.y; S.z += s2.z; S.w += s2.w;
            Q.x += q2.x; Q.y += q2.y; Q.z += q2.z; Q.w += q2.w;
        }
        atomicAdd(&gsum[g * COUT + c * 4 + 0], S.x);
        atomicAdd(&gsum[g * COUT + c * 4 + 1], S.y);
        atomicAdd(&gsum[g * COUT + c * 4 + 2], S.z);
        atomicAdd(&gsum[g * COUT + c * 4 + 3], S.w);
        atomicAdd(&gsq[g * COUT + c * 4 + 0], Q.x);
        atomicAdd(&gsq[g * COUT + c * 4 + 1], Q.y);
        atomicAdd(&gsq[g * COUT + c * 4 + 2], Q.z);
        atomicAdd(&gsq[g * COUT + c * 4 + 3], Q.w);
    }
    if (tid < NG) {
        const int c = redC[0][tid] + redC[1][tid] + redC[2][tid] + redC[3][tid];
        if (c) atomicAdd(&gcnt[tid], (float)c);
    }
}

// ---------------- Kernel B: fold BN stats into scale/shift ----------------
__global__ __launch_bounds__(NG * COUT) void norm_kernel(
    const float* __restrict__ gsum, const float* __restrict__ gsq,
    const float* __restrict__ gcnt, const float* __restrict__ gamma,
    const float* __restrict__ beta, float* __restrict__ scale,
    float* __restrict__ shift)
{
    const int t = threadIdx.x;          // 320 threads; t = g*64 + c
    const int g = t >> 6;
    const float cnt = gcnt[g] * (float)P;
    const float denom = fmaxf(cnt, 1.f);
    const float mean = gsum[t] / denom;
    const float var = gsq[t] / denom - mean * mean;
    const float sc = gamma[t] * rsqrtf(var + EPSV);
    scale[t] = sc;
    shift[t] = fmaf(-mean, sc, beta[t]);
}

// ---------------- Kernel C: recompute x, normalize, relu, max-over-P, write ----------------
// One wave per voxel iteration; NO __syncthreads in the main loop.
__global__ __launch_bounds__(256) void out_kernel(
    const float* __restrict__ inputs, const int* __restrict__ num,
    const float* __restrict__ W, const float* __restrict__ scale,
    const float* __restrict__ shift, float* __restrict__ out, int N)
{
    __shared__ float Ws[NG * CIN * COUT];
    __shared__ float4 scs[NG * 16];
    __shared__ float4 shs[NG * 16];

    const int tid = threadIdx.x;
    for (int i = tid; i < NG * CIN * COUT / 4; i += 256)
        ((float4*)Ws)[i] = ((const float4*)W)[i];
    if (tid < NG * 16) {
        scs[tid] = ((const float4*)scale)[tid];
        shs[tid] = ((const float4*)shift)[tid];
    }
    __syncthreads();

    const int lane = tid & 63, wv = tid >> 6;
    const int c4 = lane & 15, pb = lane >> 4;
    const int gw = blockIdx.x * 4 + wv;
    const int stride = gridDim.x * 4;

    for (int v = gw; v < N; v += stride) {
        const int g = group_of(num[v]);
        const float* inrow = inputs + (size_t)v * (P * CIN);
        float4 w[CIN];
        const float4* Wg = (const float4*)(Ws + g * CIN * COUT);
        #pragma unroll
        for (int i = 0; i < CIN; ++i) w[i] = Wg[i * 16 + c4];
        const float4 sc = scs[g * 16 + c4];
        const float4 sh = shs[g * 16 + c4];
        float4* outv = (float4*)out + (size_t)v * (P * 2 * COUT / 4);  // v*1024 float4s

        float4 m = f4zero();  // relu => 0 is a safe identity
        #pragma unroll
        for (int k = 0; k < 8; ++k) {
            const int p = pb + k * 4;
            const float4 acc = dot_row(inrow + p * CIN, w);
            float4 y;
            y.x = fmaxf(fmaf(acc.x, sc.x, sh.x), 0.f);
            y.y = fmaxf(fmaf(acc.y, sc.y, sh.y), 0.f);
            y.z = fmaxf(fmaf(acc.z, sc.z, sh.z), 0.f);
            y.w = fmaxf(fmaf(acc.w, sc.w, sh.w), 0.f);
            outv[p * 32 + c4] = y;
            m.x = fmaxf(m.x, y.x); m.y = fmaxf(m.y, y.y);
            m.z = fmaxf(m.z, y.z); m.w = fmaxf(m.w, y.w);
        }
        #pragma unroll
        for (int msk = 16; msk <= 32; msk <<= 1) {  // butterfly: all lanes get the max
            m.x = fmaxf(m.x, __shfl_xor(m.x, msk));
            m.y = fmaxf(m.y, __shfl_xor(m.y, msk));
            m.z = fmaxf(m.z, __shfl_xor(m.z, msk));
            m.w = fmaxf(m.w, __shfl_xor(m.w, msk));
        }
        #pragma unroll
        for (int k = 0; k < 8; ++k) {
            const int p = pb + k * 4;
            outv[p * 32 + 16 + c4] = m;
        }
    }
}

extern "C" void kernel_launch(void* const* d_in, const int* in_sizes, int n_in,
                              void* d_out, int out_size, void* d_ws, size_t ws_size,
                              hipStream_t stream)
{
    (void)n_in; (void)out_size; (void)ws_size;
    const float* inputs = (const float*)d_in[0];
    const int*   num    = (const int*)d_in[1];
    const float* W      = (const float*)d_in[2];
    const float* gamma  = (const float*)d_in[3];
    const float* beta   = (const float*)d_in[4];
    float* out = (float*)d_out;
    const int N = in_sizes[1];

    float* ws    = (float*)d_ws;
    float* gsum  = ws;          // 320
    float* gsq   = ws + 320;    // 320
    float* gcnt  = ws + 640;    // 5 (pad to 656 for 16B alignment of scale)
    float* scale = ws + 656;    // 320
    float* shift = ws + 976;    // 320

    hipMemsetAsync(d_ws, 0, 648 * sizeof(float), stream);

    int gridA = (N + 3) / 4;            // one wave per voxel max
    if (gridA > 1024) gridA = 1024;     // 4 blocks/CU, 16 waves/CU
    stats_kernel<<<gridA, 256, 0, stream>>>(inputs, num, W, gsum, gsq, gcnt, N);
    norm_kernel<<<1, NG * COUT, 0, stream>>>(gsum, gsq, gcnt, gamma, beta, scale, shift);
    int gridC = (N + 3) / 4;
    if (gridC > 2048) gridC = 2048;     // ~5 voxels per wave, W-load amortized
    out_kernel<<<gridC, 256, 0, stream>>>(inputs, num, W, scale, shift, out, N);
}

// Round 4
// 804.056 us; speedup vs baseline: 1.0490x; 1.0420x over previous
//
#include <hip/hip_runtime.h>

#define P 32
#define CIN 10
#define COUT 64
#define NG 5
#define EPSV 1e-3f

typedef float nfloat4 __attribute__((ext_vector_type(4)));  // native vec for nontemporal builtins

__device__ __forceinline__ int group_of(int nv) {
    return nv < 2 ? 0 : nv < 3 ? 1 : nv < 4 ? 2 : nv < 16 ? 3 : 4;
}

__device__ __forceinline__ float4 f4zero() { return make_float4(0.f, 0.f, 0.f, 0.f); }

__device__ __forceinline__ void nt_store4(float4 v, float4* p) {
    nfloat4 t; t.x = v.x; t.y = v.y; t.z = v.z; t.w = v.w;
    __builtin_nontemporal_store(t, (nfloat4*)p);
}

// acc(4ch) = row[0..9] . w[0..9]   (row is 8B-aligned: p*10 floats)
__device__ __forceinline__ float4 dot_row(const float* __restrict__ row,
                                          const float4* __restrict__ w) {
    const float2* r = (const float2*)row;
    const float2 a0 = r[0], a1 = r[1], a2 = r[2], a3 = r[3], a4 = r[4];
    float4 acc;
    acc.x = a0.x * w[0].x; acc.y = a0.x * w[0].y; acc.z = a0.x * w[0].z; acc.w = a0.x * w[0].w;
    acc.x = fmaf(a0.y, w[1].x, acc.x); acc.y = fmaf(a0.y, w[1].y, acc.y);
    acc.z = fmaf(a0.y, w[1].z, acc.z); acc.w = fmaf(a0.y, w[1].w, acc.w);
    acc.x = fmaf(a1.x, w[2].x, acc.x); acc.y = fmaf(a1.x, w[2].y, acc.y);
    acc.z = fmaf(a1.x, w[2].z, acc.z); acc.w = fmaf(a1.x, w[2].w, acc.w);
    acc.x = fmaf(a1.y, w[3].x, acc.x); acc.y = fmaf(a1.y, w[3].y, acc.y);
    acc.z = fmaf(a1.y, w[3].z, acc.z); acc.w = fmaf(a1.y, w[3].w, acc.w);
    acc.x = fmaf(a2.x, w[4].x, acc.x); acc.y = fmaf(a2.x, w[4].y, acc.y);
    acc.z = fmaf(a2.x, w[4].z, acc.z); acc.w = fmaf(a2.x, w[4].w, acc.w);
    acc.x = fmaf(a2.y, w[5].x, acc.x); acc.y = fmaf(a2.y, w[5].y, acc.y);
    acc.z = fmaf(a2.y, w[5].z, acc.z); acc.w = fmaf(a2.y, w[5].w, acc.w);
    acc.x = fmaf(a3.x, w[6].x, acc.x); acc.y = fmaf(a3.x, w[6].y, acc.y);
    acc.z = fmaf(a3.x, w[6].z, acc.z); acc.w = fmaf(a3.x, w[6].w, acc.w);
    acc.x = fmaf(a3.y, w[7].x, acc.x); acc.y = fmaf(a3.y, w[7].y, acc.y);
    acc.z = fmaf(a3.y, w[7].z, acc.z); acc.w = fmaf(a3.y, w[7].w, acc.w);
    acc.x = fmaf(a4.x, w[8].x, acc.x); acc.y = fmaf(a4.x, w[8].y, acc.y);
    acc.z = fmaf(a4.x, w[8].z, acc.z); acc.w = fmaf(a4.x, w[8].w, acc.w);
    acc.x = fmaf(a4.y, w[9].x, acc.x); acc.y = fmaf(a4.y, w[9].y, acc.y);
    acc.z = fmaf(a4.y, w[9].z, acc.z); acc.w = fmaf(a4.y, w[9].w, acc.w);
    return acc;
}

// ---------------- Kernel A: per-group sum / sumsq / voxel count ----------------
__global__ __launch_bounds__(256) void stats_kernel(
    const float* __restrict__ inputs, const int* __restrict__ num,
    const float* __restrict__ W, float* __restrict__ gsum,
    float* __restrict__ gsq, float* __restrict__ gcnt, int N)
{
    __shared__ float Ws[NG * CIN * COUT];        // 12.8 KB
    __shared__ float4 redS[4][NG][16];           // wave-private slots
    __shared__ float4 redQ[4][NG][16];
    __shared__ int   redC[4][NG];

    const int tid = threadIdx.x;
    for (int i = tid; i < NG * CIN * COUT / 4; i += 256)
        ((float4*)Ws)[i] = ((const float4*)W)[i];
    for (int i = tid; i < 4 * NG * 16; i += 256) {
        ((float4*)redS)[i] = f4zero();
        ((float4*)redQ)[i] = f4zero();
    }
    if (tid < 4 * NG) ((int*)redC)[tid] = 0;
    __syncthreads();

    const int lane = tid & 63, wv = tid >> 6;
    const int c4 = lane & 15, pb = lane >> 4;
    const int gw = blockIdx.x * 4 + wv;
    const int stride = gridDim.x * 4;
    int cnt0 = 0, cnt1 = 0, cnt2 = 0, cnt3 = 0, cnt4 = 0;

    for (int v = gw; v < N; v += stride) {
        const int g = group_of(num[v]);
        const float* inrow = inputs + (size_t)v * (P * CIN);
        float4 w[CIN];
        const float4* Wg = (const float4*)(Ws + g * CIN * COUT);
        #pragma unroll
        for (int i = 0; i < CIN; ++i) w[i] = Wg[i * 16 + c4];

        float4 s = f4zero(), q = f4zero();
        #pragma unroll
        for (int k = 0; k < 8; ++k) {
            const int p = pb + k * 4;
            const float4 acc = dot_row(inrow + p * CIN, w);
            s.x += acc.x; s.y += acc.y; s.z += acc.z; s.w += acc.w;
            q.x = fmaf(acc.x, acc.x, q.x); q.y = fmaf(acc.y, acc.y, q.y);
            q.z = fmaf(acc.z, acc.z, q.z); q.w = fmaf(acc.w, acc.w, q.w);
        }
        #pragma unroll
        for (int msk = 16; msk <= 32; msk <<= 1) {
            s.x += __shfl_xor(s.x, msk); s.y += __shfl_xor(s.y, msk);
            s.z += __shfl_xor(s.z, msk); s.w += __shfl_xor(s.w, msk);
            q.x += __shfl_xor(q.x, msk); q.y += __shfl_xor(q.y, msk);
            q.z += __shfl_xor(q.z, msk); q.w += __shfl_xor(q.w, msk);
        }
        if (lane < 16) {
            float4 S = redS[wv][g][c4];
            S.x += s.x; S.y += s.y; S.z += s.z; S.w += s.w;
            redS[wv][g][c4] = S;
            float4 Q = redQ[wv][g][c4];
            Q.x += q.x; Q.y += q.y; Q.z += q.z; Q.w += q.w;
            redQ[wv][g][c4] = Q;
        }
        switch (g) {
            case 0: cnt0++; break; case 1: cnt1++; break; case 2: cnt2++; break;
            case 3: cnt3++; break; default: cnt4++; break;
        }
    }
    if (lane == 0) {
        redC[wv][0] = cnt0; redC[wv][1] = cnt1; redC[wv][2] = cnt2;
        redC[wv][3] = cnt3; redC[wv][4] = cnt4;
    }
    __syncthreads();

    if (tid < NG * 16) {
        const int g = tid >> 4, c = tid & 15;
        float4 S = redS[0][g][c], Q = redQ[0][g][c];
        #pragma unroll
        for (int wvi = 1; wvi < 4; ++wvi) {
            const float4 s2 = redS[wvi][g][c], q2 = redQ[wvi][g][c];
            S.x += s2.x; S.y += s2.y; S.z += s2.z; S.w += s2.w;
            Q.x += q2.x; Q.y += q2.y; Q.z += q2.z; Q.w += q2.w;
        }
        atomicAdd(&gsum[g * COUT + c * 4 + 0], S.x);
        atomicAdd(&gsum[g * COUT + c * 4 + 1], S.y);
        atomicAdd(&gsum[g * COUT + c * 4 + 2], S.z);
        atomicAdd(&gsum[g * COUT + c * 4 + 3], S.w);
        atomicAdd(&gsq[g * COUT + c * 4 + 0], Q.x);
        atomicAdd(&gsq[g * COUT + c * 4 + 1], Q.y);
        atomicAdd(&gsq[g * COUT + c * 4 + 2], Q.z);
        atomicAdd(&gsq[g * COUT + c * 4 + 3], Q.w);
    }
    if (tid < NG) {
        const int c = redC[0][tid] + redC[1][tid] + redC[2][tid] + redC[3][tid];
        if (c) atomicAdd(&gcnt[tid], (float)c);
    }
}

// ---------------- Kernel B: fold BN stats into scale/shift ----------------
__global__ __launch_bounds__(NG * COUT) void norm_kernel(
    const float* __restrict__ gsum, const float* __restrict__ gsq,
    const float* __restrict__ gcnt, const float* __restrict__ gamma,
    const float* __restrict__ beta, float* __restrict__ scale,
    float* __restrict__ shift)
{
    const int t = threadIdx.x;          // 320 threads; t = g*64 + c
    const int g = t >> 6;
    const float cnt = gcnt[g] * (float)P;
    const float denom = fmaxf(cnt, 1.f);
    const float mean = gsum[t] / denom;
    const float var = gsq[t] / denom - mean * mean;
    const float sc = gamma[t] * rsqrtf(var + EPSV);
    scale[t] = sc;
    shift[t] = fmaf(-mean, sc, beta[t]);
}

// ---------------- Kernel C: one voxel per wave, no LDS, no barriers ----------------
__global__ __launch_bounds__(256) void out_kernel(
    const float* __restrict__ inputs, const int* __restrict__ num,
    const float* __restrict__ W, const float* __restrict__ scale,
    const float* __restrict__ shift, float* __restrict__ out, int N)
{
    const int tid = threadIdx.x;
    const int lane = tid & 63, wv = tid >> 6;
    const int c4 = lane & 15, pb = lane >> 4;
    const int v = blockIdx.x * 4 + wv;
    if (v >= N) return;

    // g is wave-uniform: pin it to an SGPR so W/scale/shift bases are scalar
    const int g = __builtin_amdgcn_readfirstlane(group_of(num[v]));

    // W fragment straight from global: 12.8 KB total, L1-resident, 4-way
    // same-address broadcast per load instruction
    const float4* Wg = (const float4*)W + g * (CIN * 16);
    float4 w[CIN];
    #pragma unroll
    for (int i = 0; i < CIN; ++i) w[i] = Wg[i * 16 + c4];
    const float4 sc = ((const float4*)scale)[g * 16 + c4];
    const float4 sh = ((const float4*)shift)[g * 16 + c4];

    const float* inrow = inputs + (size_t)v * (P * CIN);
    float4* outv = (float4*)out + (size_t)v * (P * 2 * COUT / 4);  // 1024 float4 per voxel

    float4 m = f4zero();  // relu => 0 is a safe identity
    #pragma unroll
    for (int k = 0; k < 8; ++k) {
        const int p = pb + k * 4;
        const float4 acc = dot_row(inrow + p * CIN, w);
        float4 y;
        y.x = fmaxf(fmaf(acc.x, sc.x, sh.x), 0.f);
        y.y = fmaxf(fmaf(acc.y, sc.y, sh.y), 0.f);
        y.z = fmaxf(fmaf(acc.z, sc.z, sh.z), 0.f);
        y.w = fmaxf(fmaf(acc.w, sc.w, sh.w), 0.f);
        nt_store4(y, &outv[p * 32 + c4]);
        m.x = fmaxf(m.x, y.x); m.y = fmaxf(m.y, y.y);
        m.z = fmaxf(m.z, y.z); m.w = fmaxf(m.w, y.w);
    }
    #pragma unroll
    for (int msk = 16; msk <= 32; msk <<= 1) {  // butterfly: all lanes get the max
        m.x = fmaxf(m.x, __shfl_xor(m.x, msk));
        m.y = fmaxf(m.y, __shfl_xor(m.y, msk));
        m.z = fmaxf(m.z, __shfl_xor(m.z, msk));
        m.w = fmaxf(m.w, __shfl_xor(m.w, msk));
    }
    #pragma unroll
    for (int k = 0; k < 8; ++k) {
        const int p = pb + k * 4;
        nt_store4(m, &outv[p * 32 + 16 + c4]);
    }
}

extern "C" void kernel_launch(void* const* d_in, const int* in_sizes, int n_in,
                              void* d_out, int out_size, void* d_ws, size_t ws_size,
                              hipStream_t stream)
{
    (void)n_in; (void)out_size; (void)ws_size;
    const float* inputs = (const float*)d_in[0];
    const int*   num    = (const int*)d_in[1];
    const float* W      = (const float*)d_in[2];
    const float* gamma  = (const float*)d_in[3];
    const float* beta   = (const float*)d_in[4];
    float* out = (float*)d_out;
    const int N = in_sizes[1];

    float* ws    = (float*)d_ws;
    float* gsum  = ws;          // 320
    float* gsq   = ws + 320;    // 320
    float* gcnt  = ws + 640;    // 5 (pad to 656 for 16B alignment of scale)
    float* scale = ws + 656;    // 320
    float* shift = ws + 976;    // 320

    (void)hipMemsetAsync(d_ws, 0, 648 * sizeof(float), stream);

    int gridA = (N + 3) / 4;
    if (gridA > 1024) gridA = 1024;
    stats_kernel<<<gridA, 256, 0, stream>>>(inputs, num, W, gsum, gsq, gcnt, N);
    norm_kernel<<<1, NG * COUT, 0, stream>>>(gsum, gsq, gcnt, gamma, beta, scale, shift);
    int gridC = (N + 3) / 4;   // exactly one wave per voxel
    out_kernel<<<gridC, 256, 0, stream>>>(inputs, num, W, scale, shift, out, N);
}